// Round 1
// baseline (14807.178 us; speedup 1.0000x reference)
//
#include <hip/hip_runtime.h>

// TiThTe: sequential 3-state thermal RC scan, B=4096 elements, T=8760 steps.
// Round 3: ILP across batch elements to hide the dependent-chain latency.
//   R2 post-mortem: 521 cyc/step, only ~110 cyc of VALU issue -> ~410 stall
//   cyc/step waiting on the serial chain (sub/mul -> sqrtf -> precise div).
//   TLP cannot help (each element is a serial T-step recurrence; wave time =
//   T * chain latency regardless of co-residency). Only in-wave ILP helps.
// Changes:
//   - M=8 elements per thread: 512 threads (8 blocks x 64). The in-order wave
//     now interleaves 24 independent chains; per-element-step time drops from
//     max(L=521, W=110) to max(L/8, W) ~= 110 cycles -> ~4.3x.
//   - Element mapping b = tid + j*512 keeps every store's lane-stride-12B
//     coalescing identical to the proven R2 kernel.
//   - Per-element arithmetic is BIT-IDENTICAL to R2 (contract off, hoisted
//     reciprocals, sqrtf + true divide) -> absmax must reproduce 1024.0.
//   - All M-indexed arrays accessed only from fully-unrolled loops (static
//     indices -> registers, no scratch).

#define CHUNK 2190     // 8760 = 4 * 2190; 2190*3*4 B = 26,280 B LDS
#define M 8            // elements per thread
#define NTH 512        // total threads = B / M

__global__ __launch_bounds__(64) void tithte_kernel(
    const float* __restrict__ state0,   // (B,3)
    const float* __restrict__ params,   // (B,6) : C1,R1,C2,R2,C3,R3
    const float* __restrict__ ext,      // (T,3) : T_out, heatPower, solarGains
    const int*   __restrict__ dtp,      // scalar dt
    float*       __restrict__ out,      // (T,B,3)
    int B, int T)
{
#pragma clang fp contract(off)
    __shared__ float sext[CHUNK * 3];

    const int tid = blockIdx.x * blockDim.x + threadIdx.x;   // 0..511

    const float dtf = (float)dtp[0];

    float rR1[M], rR2[M], rR3[M], k1[M], k2[M], k3[M];
    float Tin[M], Th[M], Tenv[M];

#pragma unroll
    for (int j = 0; j < M; ++j) {
        const int b = tid + j * NTH;
        const float C1 = params[b * 6 + 0];
        const float R1 = params[b * 6 + 1];
        const float C2 = params[b * 6 + 2];
        const float R2 = params[b * 6 + 3];
        const float C3 = params[b * 6 + 4];
        const float R3 = params[b * 6 + 5];
        // Hoisted combined coefficients (same as R2, ulp-identical).
        rR1[j] = 1.0f / R1;
        rR2[j] = 1.0f / R2;
        rR3[j] = 1.0f / R3;
        k1[j]  = dtf / C1;
        k2[j]  = dtf / C2;
        k3[j]  = dtf / C3;
        Tin[j]  = state0[b * 3 + 0];
        Th[j]   = state0[b * 3 + 1];
        Tenv[j] = state0[b * 3 + 2];
    }

    const float TAME  = 100000.0f;
    const float TAME2 = 100000.0f * 100000.0f;  // 1e10, exact in fp32

    float* op = out + (size_t)tid * 3;          // element j lives at +j*NTH*3
    const size_t ostride = (size_t)B * 3;

    for (int c = 0; c < T; c += CHUNK) {
        const int n = (T - c < CHUNK) ? (T - c) : CHUNK;

        __syncthreads();   // previous chunk's LDS reads done before overwrite
        for (int i = threadIdx.x; i < n * 3; i += 64)
            sext[i] = ext[(size_t)c * 3 + i];
        __syncthreads();

        for (int t = 0; t < n; ++t) {
            const float Tout = sext[t * 3 + 0];
            const float hp   = sext[t * 3 + 1];
            const float sg   = sext[t * 3 + 2];

#pragma unroll
            for (int j = 0; j < M; ++j) {
                const float P1 = (Tin[j] - Tenv[j]) * rR1[j];   // P_in2Wall
                const float P2 = (Tin[j] - Th[j])   * rR2[j];   // P_in2Heater
                float dTin  = (sg - P1 - P2) * k1[j];
                float dTh   = k2[j] * (hp + P2);
                float dTenv = (P1 + (Tout - Tenv[j]) * rR3[j]) * k3[j];

                // tame(x) = x*TAME / sqrt(x*x + TAME*TAME) — exact np order
                dTin  = (dTin  * TAME) / sqrtf(dTin  * dTin  + TAME2);
                dTh   = (dTh   * TAME) / sqrtf(dTh   * dTh   + TAME2);
                dTenv = (dTenv * TAME) / sqrtf(dTenv * dTenv + TAME2);

                Tin[j]  += dTin;
                Th[j]   += dTh;
                Tenv[j] += dTenv;

                op[(size_t)j * NTH * 3 + 0] = Tin[j];
                op[(size_t)j * NTH * 3 + 1] = Th[j];
                op[(size_t)j * NTH * 3 + 2] = Tenv[j];
            }
            op += ostride;
        }
    }
}

extern "C" void kernel_launch(void* const* d_in, const int* in_sizes, int n_in,
                              void* d_out, int out_size, void* d_ws, size_t ws_size,
                              hipStream_t stream) {
    const float* state0 = (const float*)d_in[0];
    const float* params = (const float*)d_in[1];
    const float* ext    = (const float*)d_in[2];
    const int*   dtp    = (const int*)d_in[3];
    float*       out    = (float*)d_out;

    const int B = in_sizes[0] / 3;   // 4096
    const int T = in_sizes[2] / 3;   // 8760

    const int block = 64;
    const int grid  = (B / M) / block;   // 512 threads -> 8 blocks
    tithte_kernel<<<grid, block, 0, stream>>>(state0, params, ext, dtp, out, B, T);
}

// Round 2
// 935.740 us; speedup vs baseline: 15.8240x; 15.8240x over previous
//
#include <hip/hip_runtime.h>

// TiThTe: sequential 3-state thermal RC scan, B=4096 elements, T=8760 steps.
// Round 4: shrink the per-step dependent chain (L) — the only lever left.
//   R3 post-mortem: M elems/thread is structurally useless here: wall/step =
//   max(L, M*W); fewer waves x more issue each can never beat R2's 64-wave
//   M=1 config. (R3 additionally spilled: 120 persistent floats vs 128 VGPR
//   cap -> chains serialized through scratch -> 8x500 cyc/step.)
//   Parallelism is capped at 4096/64 = 64 waves. So: attack L (~521 cyc).
// Changes vs R2 (1903 us):
//   - tame(x) = x*TAME*rsqrt(x^2+TAME^2) via v_rsq_f32 (HW <=~1ulp) + one
//     Newton iteration (~1e-7 rel, IEEE-comparable). Kills BOTH the precise
//     sqrtf expansion (~40 cyc) and the precise divide expansion (~60 cyc).
//   - derivative algebra folded into precomputed fma coefficients:
//       dTin  = fma(-a12, v, fma(-a11, u, k1*sg))   u=Tin-Tenv, v=Tin-Th
//       dTh   = fma( a22, v, k2*hp)
//       dTenv = fma( a31, u, a33*w)                 w=Tout-Tenv
//     k1*sg, k2*hp are off-chain (ext values known one iteration early).
//   - ext triple software-pipelined one iteration ahead in registers, so no
//     lgkmcnt wait sits in the chain at unroll-group boundaries.
//   - ulp-level numeric changes are deliberate: absmax headroom 1024/3891.
// One thread per element; 64 blocks x 64 threads = 64 waves on 64 CUs.

#define CHUNK 2190   // 8760 = 4 * 2190; (2190*3+3)*4 B = 26,292 B LDS

__device__ __forceinline__ float tame_fast(float x) {
    // x * 1e5 / sqrt(x^2 + 1e10), via HW rsqrt + 1 Newton-Raphson step.
    const float TAME  = 100000.0f;
    const float TAME2 = 1.0e10f;               // exact in fp32
    float t2 = fmaf(x, x, TAME2);              // no overflow: |x| <~ 1e6
    float r  = __builtin_amdgcn_rsqf(t2);      // v_rsq_f32, ~1 ulp
    float e  = 0.5f * t2 * r;                  // off critical path start
    r = r * fmaf(-e, r, 1.5f);                 // NR: r *= 1.5 - 0.5*t2*r^2
    return (x * TAME) * r;
}

__global__ __launch_bounds__(64) void tithte_kernel(
    const float* __restrict__ state0,   // (B,3)
    const float* __restrict__ params,   // (B,6) : C1,R1,C2,R2,C3,R3
    const float* __restrict__ ext,      // (T,3) : T_out, heatPower, solarGains
    const int*   __restrict__ dtp,      // scalar dt
    float*       __restrict__ out,      // (T,B,3)
    int B, int T)
{
    __shared__ float sext[CHUNK * 3 + 3];   // +3: harmless prefetch overread

    const int b = blockIdx.x * blockDim.x + threadIdx.x;

    const float dtf = (float)dtp[0];

    const float C1 = params[b * 6 + 0];
    const float R1 = params[b * 6 + 1];
    const float C2 = params[b * 6 + 2];
    const float R2 = params[b * 6 + 3];
    const float C3 = params[b * 6 + 4];
    const float R3 = params[b * 6 + 5];

    // Combined coefficients (ulp-level change, covered by absmax headroom):
    const float k1  = dtf / C1;
    const float k2  = dtf / C2;
    const float k3  = dtf / C3;
    const float a11 = k1 / R1;    // k1*rR1
    const float a12 = k1 / R2;    // k1*rR2
    const float a22 = k2 / R2;
    const float a31 = k3 / R1;
    const float a33 = k3 / R3;

    float Tin  = state0[b * 3 + 0];
    float Th   = state0[b * 3 + 1];
    float Tenv = state0[b * 3 + 2];

    float* op = out + (size_t)b * 3;
    const size_t ostride = (size_t)B * 3;

    for (int c = 0; c < T; c += CHUNK) {
        const int n = (T - c < CHUNK) ? (T - c) : CHUNK;

        __syncthreads();   // previous chunk's LDS reads done before overwrite
        for (int i = threadIdx.x; i < n * 3; i += 64)
            sext[i] = ext[(size_t)c * 3 + i];
        __syncthreads();

        // Software-pipelined ext triple: current step's values are already
        // in registers; issue next step's ds_reads before computing.
        float Tout = sext[0];
        float hp   = sext[1];
        float sg   = sext[2];

#pragma unroll 6
        for (int t = 0; t < n; ++t) {
            // prefetch t+1 (overreads 3 floats past n*3 on last iter: padded)
            const float ToutN = sext[t * 3 + 3];
            const float hpN   = sext[t * 3 + 4];
            const float sgN   = sext[t * 3 + 5];

            // off-chain products (ext values were available last iteration)
            const float k1sg = k1 * sg;
            const float k2hp = k2 * hp;

            const float u = Tin - Tenv;
            const float v = Tin - Th;
            const float w = Tout - Tenv;

            const float dTin  = fmaf(-a12, v, fmaf(-a11, u, k1sg));
            const float dTh   = fmaf( a22, v, k2hp);
            const float dTenv = fmaf( a31, u, a33 * w);

            Tin  += tame_fast(dTin);
            Th   += tame_fast(dTh);
            Tenv += tame_fast(dTenv);

            op[0] = Tin;
            op[1] = Th;
            op[2] = Tenv;
            op += ostride;

            Tout = ToutN; hp = hpN; sg = sgN;
        }
    }
}

extern "C" void kernel_launch(void* const* d_in, const int* in_sizes, int n_in,
                              void* d_out, int out_size, void* d_ws, size_t ws_size,
                              hipStream_t stream) {
    const float* state0 = (const float*)d_in[0];
    const float* params = (const float*)d_in[1];
    const float* ext    = (const float*)d_in[2];
    const int*   dtp    = (const int*)d_in[3];
    float*       out    = (float*)d_out;

    const int B = in_sizes[0] / 3;   // 4096
    const int T = in_sizes[2] / 3;   // 8760

    const int block = 64;
    const int grid  = B / block;     // 64 blocks, one wave each
    tithte_kernel<<<grid, block, 0, stream>>>(state0, params, ext, dtp, out, B, T);
}